// Round 1
// baseline (813.051 us; speedup 1.0000x reference)
//
#include <hip/hip_runtime.h>
#include <hip/hip_bf16.h>
#include <math.h>

#define HIDDEN 256
#define NHEAD 8
#define DK 32
#define INV_SCALE 0.17677669529663687f  /* 1/sqrt(32) */

// ---------------- CSR build ----------------

__global__ __launch_bounds__(256) void hist_kernel(const int* __restrict__ dst,
                                                   int* __restrict__ deg, int E) {
  int e = blockIdx.x * blockDim.x + threadIdx.x;
  if (e < E) atomicAdd(&deg[dst[e]], 1);
}

// 2-level exclusive scan: block of 256 threads scans 1024 elements.
__global__ __launch_bounds__(256) void scan1_kernel(const int* __restrict__ deg,
                                                    int* __restrict__ offs,
                                                    int* __restrict__ bsums, int N) {
  __shared__ int s[256];
  int tid = threadIdx.x;
  int base = blockIdx.x * 1024 + tid * 4;
  int v0 = (base + 0 < N) ? deg[base + 0] : 0;
  int v1 = (base + 1 < N) ? deg[base + 1] : 0;
  int v2 = (base + 2 < N) ? deg[base + 2] : 0;
  int v3 = (base + 3 < N) ? deg[base + 3] : 0;
  int tsum = v0 + v1 + v2 + v3;
  s[tid] = tsum;
  __syncthreads();
  for (int off = 1; off < 256; off <<= 1) {
    int t = (tid >= off) ? s[tid - off] : 0;
    __syncthreads();
    s[tid] += t;
    __syncthreads();
  }
  int excl = s[tid] - tsum;
  if (base + 0 < N) offs[base + 0] = excl;
  if (base + 1 < N) offs[base + 1] = excl + v0;
  if (base + 2 < N) offs[base + 2] = excl + v0 + v1;
  if (base + 3 < N) offs[base + 3] = excl + v0 + v1 + v2;
  if (tid == 255) bsums[blockIdx.x] = s[255];
}

__global__ void scan2_kernel(int* __restrict__ bsums, int nb) {
  if (blockIdx.x == 0 && threadIdx.x == 0) {
    int run = 0;
    for (int b = 0; b < nb; ++b) { int t = bsums[b]; bsums[b] = run; run += t; }
  }
}

__global__ __launch_bounds__(256) void scan3_kernel(int* __restrict__ offs,
                                                    int* __restrict__ cursor,
                                                    const int* __restrict__ bsums,
                                                    int N, int E) {
  int i = blockIdx.x * blockDim.x + threadIdx.x;
  if (i < N) {
    int v = offs[i] + bsums[i >> 10];
    offs[i] = v;
    cursor[i] = v;
  }
  if (i == 0) offs[N] = E;
}

__global__ __launch_bounds__(256) void scatter_kernel(const int* __restrict__ dst,
                                                      int* __restrict__ cursor,
                                                      int* __restrict__ eids, int E) {
  int e = blockIdx.x * blockDim.x + threadIdx.x;
  if (e < E) {
    int n = dst[e];
    int pos = atomicAdd(&cursor[n], 1);
    eids[pos] = e;
  }
}

// ---------------- fp32 tiled GEMM:  C[M,256] = A[M,256] @ W[256,256]^T (+bias) ----------------
#define BM 64
#define BN 64
#define BK 16

__global__ __launch_bounds__(256) void gemm_bias_kernel(const float* __restrict__ A,
                                                        const float* __restrict__ W,
                                                        const float* __restrict__ bias,
                                                        float* __restrict__ C, int M) {
  __shared__ float As[BK][BM + 4];
  __shared__ float Bs[BK][BN + 4];
  int tid = threadIdx.x;
  int brow = blockIdx.x * BM;
  int bcol = blockIdx.y * BN;

  float acc[4][4] = {};

  int lm = tid >> 2;        // 0..63  (row within tile for loads)
  int lk = (tid & 3) * 4;   // 0,4,8,12
  int arow = brow + lm; if (arow >= M) arow = M - 1;
  const float* Arow = &A[(size_t)arow * HIDDEN];
  const float* Wrow = &W[(size_t)(bcol + lm) * HIDDEN];

  int tm = (tid >> 4) * 4;  // 0,4,..,60
  int tn = (tid & 15) * 4;

  for (int k0 = 0; k0 < HIDDEN; k0 += BK) {
    float4 a = *(const float4*)&Arow[k0 + lk];
    float4 w = *(const float4*)&Wrow[k0 + lk];
    __syncthreads();
    As[lk + 0][lm] = a.x; As[lk + 1][lm] = a.y; As[lk + 2][lm] = a.z; As[lk + 3][lm] = a.w;
    Bs[lk + 0][lm] = w.x; Bs[lk + 1][lm] = w.y; Bs[lk + 2][lm] = w.z; Bs[lk + 3][lm] = w.w;
    __syncthreads();
#pragma unroll
    for (int kk = 0; kk < BK; ++kk) {
      float av[4], bv[4];
      *(float4*)av = *(const float4*)&As[kk][tm];
      *(float4*)bv = *(const float4*)&Bs[kk][tn];
#pragma unroll
      for (int i = 0; i < 4; ++i)
#pragma unroll
        for (int j = 0; j < 4; ++j) acc[i][j] += av[i] * bv[j];
    }
  }

  float bv4[4] = {0.f, 0.f, 0.f, 0.f};
  if (bias) *(float4*)bv4 = *(const float4*)&bias[bcol + tn];
#pragma unroll
  for (int i = 0; i < 4; ++i) {
    int row = brow + tm + i;
    if (row < M) {
      float out4[4];
#pragma unroll
      for (int j = 0; j < 4; ++j) out4[j] = acc[i][j] + bv4[j];
      *(float4*)&C[(size_t)row * HIDDEN + bcol + tn] = *(const float4*)out4;
    }
  }
}

// ---------------- per-dst-node attention aggregation ----------------
// block = 1 node, 256 threads; thread c -> head h=c>>5, dim d=c&31.
__global__ __launch_bounds__(256) void agg_kernel(const float* __restrict__ q,
                                                  const float* __restrict__ k,
                                                  const float* __restrict__ v,
                                                  const int* __restrict__ offs,
                                                  const int* __restrict__ eids,
                                                  const int* __restrict__ src,
                                                  float* __restrict__ o, int N) {
  int n = blockIdx.x;
  int c = threadIdx.x;
  float ql = q[(size_t)n * HIDDEN + c];
  int e0 = offs[n], e1 = offs[n + 1];
  float wv = 0.f, z = 0.f;
  for (int idx = e0; idx < e1; ++idx) {
    int e = eids[idx];
    int s = src[e];
    float kc = k[(size_t)s * HIDDEN + c];
    float p = ql * kc;
    // reduce within the 32-lane head group
    p += __shfl_xor(p, 16);
    p += __shfl_xor(p, 8);
    p += __shfl_xor(p, 4);
    p += __shfl_xor(p, 2);
    p += __shfl_xor(p, 1);
    float sarg = p * INV_SCALE;
    sarg = fminf(fmaxf(sarg, -10.f), 10.f);
    float sc = __expf(sarg);
    float vc = v[(size_t)s * HIDDEN + c];
    wv += sc * vc;
    z += sc;
  }
  o[(size_t)n * HIDDEN + c] = wv / z;
}

// ---------------- launch ----------------

extern "C" void kernel_launch(void* const* d_in, const int* in_sizes, int n_in,
                              void* d_out, int out_size, void* d_ws, size_t ws_size,
                              hipStream_t stream) {
  const float* inputs = (const float*)d_in[0];
  const float* Wq = (const float*)d_in[1];
  const float* bq = (const float*)d_in[2];
  const float* Wk = (const float*)d_in[3];
  const float* Wv = (const float*)d_in[4];
  const float* Wo = (const float*)d_in[5];
  const float* bo = (const float*)d_in[6];
  const int* src = (const int*)d_in[7];
  const int* dst = (const int*)d_in[8];

  int N = in_sizes[0] / HIDDEN;
  int E = in_sizes[7];

  char* w = (char*)d_ws;
  size_t NB = (size_t)N * HIDDEN * sizeof(float);
  float* q = (float*)w; w += NB;
  float* kbuf = (float*)w; w += NB;
  float* vbuf = (float*)w; w += NB;
  float* obuf = (float*)w; w += NB;
  int* deg = (int*)w; w += (size_t)N * 4;
  int* offs = (int*)w; w += (size_t)(N + 4) * 4;
  int* cursor = (int*)w; w += (size_t)N * 4;
  int* eids = (int*)w; w += (size_t)E * 4;
  int* bsums = (int*)w; w += 256 * 4;

  // CSR build
  hipMemsetAsync(deg, 0, (size_t)N * 4, stream);
  int eb = (E + 255) / 256;
  hist_kernel<<<eb, 256, 0, stream>>>(dst, deg, E);
  int nb = (N + 1023) / 1024;
  scan1_kernel<<<nb, 256, 0, stream>>>(deg, offs, bsums, N);
  scan2_kernel<<<1, 64, 0, stream>>>(bsums, nb);
  scan3_kernel<<<(N + 255) / 256, 256, 0, stream>>>(offs, cursor, bsums, N, E);
  scatter_kernel<<<eb, 256, 0, stream>>>(dst, cursor, eids, E);

  // projections
  dim3 gg((N + BM - 1) / BM, HIDDEN / BN);
  gemm_bias_kernel<<<gg, 256, 0, stream>>>(inputs, Wq, bq, q, N);
  gemm_bias_kernel<<<gg, 256, 0, stream>>>(inputs, Wk, nullptr, kbuf, N);
  gemm_bias_kernel<<<gg, 256, 0, stream>>>(inputs, Wv, nullptr, vbuf, N);

  // attention aggregation
  agg_kernel<<<N, 256, 0, stream>>>(q, kbuf, vbuf, offs, eids, src, obuf, N);

  // output projection
  gemm_bias_kernel<<<gg, 256, 0, stream>>>(obuf, Wo, bo, (float*)d_out, N);
}

// Round 2
// 304.880 us; speedup vs baseline: 2.6668x; 2.6668x over previous
//
#include <hip/hip_runtime.h>
#include <hip/hip_bf16.h>
#include <math.h>

#define HIDDEN 256
#define INV_SCALE 0.17677669529663687f  /* 1/sqrt(32) */

typedef __attribute__((ext_vector_type(8))) short short8;
typedef __attribute__((ext_vector_type(4))) float f32x4;
typedef const __attribute__((address_space(1))) unsigned int* gas_ptr;
typedef __attribute__((address_space(3))) unsigned int* las_ptr;

static __device__ __forceinline__ unsigned short f2bf(float x) {
  unsigned u = __float_as_uint(x);
  unsigned r = (u + 0x7FFF + ((u >> 16) & 1)) >> 16;
  return (unsigned short)r;
}
static __device__ __forceinline__ float bf2f(unsigned short u) {
  return __uint_as_float((unsigned)u << 16);
}

// ---------------- input / weight conversion to bf16 ----------------

__global__ __launch_bounds__(256) void conv_a_kernel(const float* __restrict__ in,
                                                     unsigned short* __restrict__ out,
                                                     int total4) {
  int stride = gridDim.x * blockDim.x;
  for (int i = blockIdx.x * blockDim.x + threadIdx.x; i < total4; i += stride) {
    float4 f = ((const float4*)in)[i];
    ushort4 u;
    u.x = f2bf(f.x); u.y = f2bf(f.y); u.z = f2bf(f.z); u.w = f2bf(f.w);
    ((ushort4*)out)[i] = u;
  }
}

// Wq,Wk,Wv -> wqkv[768][256], Wo -> wob[256][256]
__global__ __launch_bounds__(256) void conv_w_kernel(const float* __restrict__ Wq,
                                                     const float* __restrict__ Wk,
                                                     const float* __restrict__ Wv,
                                                     const float* __restrict__ Wo,
                                                     unsigned short* __restrict__ wqkv,
                                                     unsigned short* __restrict__ wob) {
  int i = blockIdx.x * 256 + threadIdx.x;  // grid 1024 -> 262144
  int m = i >> 16;
  int j = i & 65535;
  const float* s = (m == 0) ? Wq : (m == 1) ? Wk : (m == 2) ? Wv : Wo;
  unsigned short b = f2bf(s[j]);
  if (m < 3) wqkv[m * 65536 + j] = b;
  else wob[j] = b;
}

// ---------------- CSR build ----------------

__global__ __launch_bounds__(256) void hist_kernel(const int* __restrict__ dst,
                                                   int* __restrict__ deg, int E) {
  int e = blockIdx.x * blockDim.x + threadIdx.x;
  if (e < E) atomicAdd(&deg[dst[e]], 1);
}

__global__ __launch_bounds__(256) void scan1_kernel(const int* __restrict__ deg,
                                                    int* __restrict__ offs,
                                                    int* __restrict__ bsums, int N) {
  __shared__ int s[256];
  int tid = threadIdx.x;
  int base = blockIdx.x * 1024 + tid * 4;
  int v0 = (base + 0 < N) ? deg[base + 0] : 0;
  int v1 = (base + 1 < N) ? deg[base + 1] : 0;
  int v2 = (base + 2 < N) ? deg[base + 2] : 0;
  int v3 = (base + 3 < N) ? deg[base + 3] : 0;
  int tsum = v0 + v1 + v2 + v3;
  s[tid] = tsum;
  __syncthreads();
  for (int off = 1; off < 256; off <<= 1) {
    int t = (tid >= off) ? s[tid - off] : 0;
    __syncthreads();
    s[tid] += t;
    __syncthreads();
  }
  int excl = s[tid] - tsum;
  if (base + 0 < N) offs[base + 0] = excl;
  if (base + 1 < N) offs[base + 1] = excl + v0;
  if (base + 2 < N) offs[base + 2] = excl + v0 + v1;
  if (base + 3 < N) offs[base + 3] = excl + v0 + v1 + v2;
  if (tid == 255) bsums[blockIdx.x] = s[255];
}

__global__ void scan2_kernel(int* __restrict__ bsums, int nb) {
  if (blockIdx.x == 0 && threadIdx.x == 0) {
    int run = 0;
    for (int b = 0; b < nb; ++b) { int t = bsums[b]; bsums[b] = run; run += t; }
  }
}

__global__ __launch_bounds__(256) void scan3_kernel(int* __restrict__ offs,
                                                    int* __restrict__ cursor,
                                                    const int* __restrict__ bsums,
                                                    int N, int E) {
  int i = blockIdx.x * blockDim.x + threadIdx.x;
  if (i < N) {
    int v = offs[i] + bsums[i >> 10];
    offs[i] = v;
    cursor[i] = v;
  }
  if (i == 0) offs[N] = E;
}

// store src node id directly (removes eids->src dependent load in agg)
__global__ __launch_bounds__(256) void scatter_kernel(const int* __restrict__ dst,
                                                      const int* __restrict__ src,
                                                      int* __restrict__ cursor,
                                                      int* __restrict__ esrc, int E) {
  int e = blockIdx.x * blockDim.x + threadIdx.x;
  if (e < E) {
    int n = dst[e];
    int pos = atomicAdd(&cursor[n], 1);
    esrc[pos] = src[e];
  }
}

// ---------------- bf16 MFMA GEMM: C[M,Ncols] = A[M,256] @ B[Ncols,256]^T ----------------
// MODE 0: fused QKV (Ncols=768): cols 0-255 -> q fp32 (+bias), 256-511 -> k bf16, 512-767 -> v bf16
// MODE 1: out projection (Ncols=256): fp32 + bias
#define GBM 128
#define GBN 128
#define GBK 32

template <int MODE>
__global__ __launch_bounds__(256) void mfma_gemm_kernel(const unsigned short* __restrict__ A,
                                                        const unsigned short* __restrict__ B,
                                                        const float* __restrict__ bias,
                                                        float* __restrict__ Cf,
                                                        unsigned short* __restrict__ Ck,
                                                        unsigned short* __restrict__ Cv,
                                                        int M) {
  __shared__ unsigned short As[GBM][GBK];
  __shared__ unsigned short Bs[GBN][GBK];
  int tid = threadIdx.x;
  int lane = tid & 63;
  int wid = tid >> 6;
  int wm = wid >> 1, wn = wid & 1;
  int brow = blockIdx.x * GBM;
  int bcol = blockIdx.y * GBN;

  // staging: wave wid covers rows [wid*32, wid*32+32) in two 1KB calls
  int srow = wid * 32 + (lane >> 2);
  int skoff = (lane & 3) * 8;
  const unsigned short* gA0 = &A[(size_t)(brow + srow) * HIDDEN + skoff];
  const unsigned short* gA1 = gA0 + (size_t)16 * HIDDEN;
  const unsigned short* gB0 = &B[(size_t)(bcol + srow) * HIDDEN + skoff];
  const unsigned short* gB1 = gB0 + (size_t)16 * HIDDEN;
  char* ldsA = (char*)&As[0][0] + wid * 2048;
  char* ldsB = (char*)&Bs[0][0] + wid * 2048;

  f32x4 acc[4][4] = {};

  int fr = lane & 15;
  int kg = (lane >> 4) * 8;

  for (int k0 = 0; k0 < HIDDEN; k0 += GBK) {
    __syncthreads();
    __builtin_amdgcn_global_load_lds((gas_ptr)(const void*)(gA0 + k0), (las_ptr)(void*)ldsA, 16, 0, 0);
    __builtin_amdgcn_global_load_lds((gas_ptr)(const void*)(gA1 + k0), (las_ptr)(void*)(ldsA + 1024), 16, 0, 0);
    __builtin_amdgcn_global_load_lds((gas_ptr)(const void*)(gB0 + k0), (las_ptr)(void*)ldsB, 16, 0, 0);
    __builtin_amdgcn_global_load_lds((gas_ptr)(const void*)(gB1 + k0), (las_ptr)(void*)(ldsB + 1024), 16, 0, 0);
    asm volatile("s_waitcnt vmcnt(0)" ::: "memory");
    __syncthreads();
    short8 af[4], bfg[4];
#pragma unroll
    for (int mi = 0; mi < 4; ++mi)
      af[mi] = *(const short8*)&As[wm * 64 + mi * 16 + fr][kg];
#pragma unroll
    for (int ni = 0; ni < 4; ++ni)
      bfg[ni] = *(const short8*)&Bs[wn * 64 + ni * 16 + fr][kg];
#pragma unroll
    for (int mi = 0; mi < 4; ++mi)
#pragma unroll
      for (int ni = 0; ni < 4; ++ni)
        acc[mi][ni] = __builtin_amdgcn_mfma_f32_16x16x32_bf16(af[mi], bfg[ni], acc[mi][ni], 0, 0, 0);
  }

  int fq = lane >> 4;
#pragma unroll
  for (int mi = 0; mi < 4; ++mi) {
#pragma unroll
    for (int ni = 0; ni < 4; ++ni) {
      int c = bcol + wn * 64 + ni * 16 + fr;
#pragma unroll
      for (int j = 0; j < 4; ++j) {
        int r = brow + wm * 64 + mi * 16 + fq * 4 + j;
        if (r < M) {
          float val = acc[mi][ni][j];
          if (MODE == 1) {
            Cf[(size_t)r * HIDDEN + c] = val + bias[c];
          } else {
            if (c < 256) Cf[(size_t)r * HIDDEN + c] = val + bias[c];
            else if (c < 512) Ck[(size_t)r * HIDDEN + (c - 256)] = f2bf(val);
            else Cv[(size_t)r * HIDDEN + (c - 512)] = f2bf(val);
          }
        }
      }
    }
  }
}

// ---------------- per-dst-node attention aggregation ----------------
// 1 wave per node, lane t handles channels [t*4, t*4+4); head = 8-lane group.
__global__ __launch_bounds__(256) void agg_kernel(const float* __restrict__ q,
                                                  const unsigned short* __restrict__ k,
                                                  const unsigned short* __restrict__ v,
                                                  const int* __restrict__ offs,
                                                  const int* __restrict__ esrc,
                                                  unsigned short* __restrict__ o, int N) {
  int n = blockIdx.x * 4 + (threadIdx.x >> 6);
  if (n >= N) return;
  int t = threadIdx.x & 63;
  float4 qv = *(const float4*)&q[(size_t)n * HIDDEN + t * 4];
  int e0 = offs[n], e1 = offs[n + 1];
  float w0 = 0.f, w1 = 0.f, w2 = 0.f, w3 = 0.f, z = 0.f;
  int idx = e0;
  for (; idx + 2 <= e1; idx += 2) {
    int sa = esrc[idx], sb = esrc[idx + 1];
    ushort4 ka = *(const ushort4*)&k[(size_t)sa * HIDDEN + t * 4];
    ushort4 kb = *(const ushort4*)&k[(size_t)sb * HIDDEN + t * 4];
    ushort4 va = *(const ushort4*)&v[(size_t)sa * HIDDEN + t * 4];
    ushort4 vb = *(const ushort4*)&v[(size_t)sb * HIDDEN + t * 4];
    float pa = qv.x * bf2f(ka.x) + qv.y * bf2f(ka.y) + qv.z * bf2f(ka.z) + qv.w * bf2f(ka.w);
    float pb = qv.x * bf2f(kb.x) + qv.y * bf2f(kb.y) + qv.z * bf2f(kb.z) + qv.w * bf2f(kb.w);
    pa += __shfl_xor(pa, 4); pb += __shfl_xor(pb, 4);
    pa += __shfl_xor(pa, 2); pb += __shfl_xor(pb, 2);
    pa += __shfl_xor(pa, 1); pb += __shfl_xor(pb, 1);
    float ea = __expf(fminf(fmaxf(pa * INV_SCALE, -10.f), 10.f));
    float eb = __expf(fminf(fmaxf(pb * INV_SCALE, -10.f), 10.f));
    w0 += ea * bf2f(va.x) + eb * bf2f(vb.x);
    w1 += ea * bf2f(va.y) + eb * bf2f(vb.y);
    w2 += ea * bf2f(va.z) + eb * bf2f(vb.z);
    w3 += ea * bf2f(va.w) + eb * bf2f(vb.w);
    z += ea + eb;
  }
  if (idx < e1) {
    int sa = esrc[idx];
    ushort4 ka = *(const ushort4*)&k[(size_t)sa * HIDDEN + t * 4];
    ushort4 va = *(const ushort4*)&v[(size_t)sa * HIDDEN + t * 4];
    float pa = qv.x * bf2f(ka.x) + qv.y * bf2f(ka.y) + qv.z * bf2f(ka.z) + qv.w * bf2f(ka.w);
    pa += __shfl_xor(pa, 4);
    pa += __shfl_xor(pa, 2);
    pa += __shfl_xor(pa, 1);
    float ea = __expf(fminf(fmaxf(pa * INV_SCALE, -10.f), 10.f));
    w0 += ea * bf2f(va.x);
    w1 += ea * bf2f(va.y);
    w2 += ea * bf2f(va.z);
    w3 += ea * bf2f(va.w);
    z += ea;
  }
  float inv = 1.0f / z;
  ushort4 out;
  out.x = f2bf(w0 * inv); out.y = f2bf(w1 * inv);
  out.z = f2bf(w2 * inv); out.w = f2bf(w3 * inv);
  *(ushort4*)&o[(size_t)n * HIDDEN + t * 4] = out;
}

// ---------------- launch ----------------

extern "C" void kernel_launch(void* const* d_in, const int* in_sizes, int n_in,
                              void* d_out, int out_size, void* d_ws, size_t ws_size,
                              hipStream_t stream) {
  const float* inputs = (const float*)d_in[0];
  const float* Wq = (const float*)d_in[1];
  const float* bq = (const float*)d_in[2];
  const float* Wk = (const float*)d_in[3];
  const float* Wv = (const float*)d_in[4];
  const float* Wo = (const float*)d_in[5];
  const float* bo = (const float*)d_in[6];
  const int* src = (const int*)d_in[7];
  const int* dst = (const int*)d_in[8];

  int N = in_sizes[0] / HIDDEN;
  int E = in_sizes[7];
  int Mpad = N + GBM;  // pad rows so GEMM staging overrun stays in allocated ws

  char* w = (char*)d_ws;
  unsigned short* a_bf = (unsigned short*)w; w += (size_t)Mpad * HIDDEN * 2;
  float* q = (float*)w;                      w += (size_t)N * HIDDEN * 4;
  unsigned short* kb = (unsigned short*)w;   w += (size_t)N * HIDDEN * 2;
  unsigned short* vb = (unsigned short*)w;   w += (size_t)N * HIDDEN * 2;
  unsigned short* ob = (unsigned short*)w;   w += (size_t)Mpad * HIDDEN * 2;
  unsigned short* wqkv = (unsigned short*)w; w += (size_t)768 * HIDDEN * 2;
  unsigned short* wob = (unsigned short*)w;  w += (size_t)256 * HIDDEN * 2;
  int* deg = (int*)w;    w += (size_t)N * 4;
  int* offs = (int*)w;   w += (size_t)(N + 4) * 4;
  int* cursor = (int*)w; w += (size_t)N * 4;
  int* esrc = (int*)w;   w += (size_t)E * 4;
  int* bsums = (int*)w;  w += 256 * 4;

  // conversions
  conv_a_kernel<<<2048, 256, 0, stream>>>(inputs, a_bf, N * (HIDDEN / 4));
  conv_w_kernel<<<1024, 256, 0, stream>>>(Wq, Wk, Wv, Wo, wqkv, wob);

  // CSR build
  hipMemsetAsync(deg, 0, (size_t)N * 4, stream);
  int eb = (E + 255) / 256;
  hist_kernel<<<eb, 256, 0, stream>>>(dst, deg, E);
  int nb = (N + 1023) / 1024;
  scan1_kernel<<<nb, 256, 0, stream>>>(deg, offs, bsums, N);
  scan2_kernel<<<1, 64, 0, stream>>>(bsums, nb);
  scan3_kernel<<<(N + 255) / 256, 256, 0, stream>>>(offs, cursor, bsums, N, E);
  scatter_kernel<<<eb, 256, 0, stream>>>(dst, src, cursor, esrc, E);

  // fused QKV projection (bf16 MFMA)
  dim3 gqkv((N + GBM - 1) / GBM, 768 / GBN);
  mfma_gemm_kernel<0><<<gqkv, 256, 0, stream>>>(a_bf, wqkv, bq, q, kb, vb, N);

  // attention aggregation
  agg_kernel<<<(N + 3) / 4, 256, 0, stream>>>(q, kb, vb, offs, esrc, ob, N);

  // output projection
  dim3 gout((N + GBM - 1) / GBM, 256 / GBN);
  mfma_gemm_kernel<1><<<gout, 256, 0, stream>>>(ob, wob, bo, (float*)d_out, nullptr, nullptr, N);
}